// Round 1
// baseline (8315.744 us; speedup 1.0000x reference)
//
#include <hip/hip_runtime.h>
#include <hip/hip_bf16.h>

typedef __attribute__((ext_vector_type(8))) unsigned short ushortx8;
typedef __attribute__((ext_vector_type(4))) float floatx4;

#define HDIM 512
#define DDIM 64
#define TSTEPS 512
#define BATCH 256

__device__ __forceinline__ float b2f(unsigned short s) {
    union { unsigned int u; float f; } cvt;
    cvt.u = ((unsigned int)s) << 16;
    return cvt.f;
}

// Build bf16 weight copies in ws: whh0 [512][512], w1cat [512][1024] (= [w_ih1 | w_hh1]),
// and fused biases bias0 = b_ih0+b_hh0, bias1 = b_ih1+b_hh1.
__global__ void prep_kernel(const float* __restrict__ w_hh0,
                            const float* __restrict__ w_ih1,
                            const float* __restrict__ w_hh1,
                            const float* __restrict__ b_ih0,
                            const float* __restrict__ b_hh0,
                            const float* __restrict__ b_ih1,
                            const float* __restrict__ b_hh1,
                            unsigned short* __restrict__ whh0_bf,
                            unsigned short* __restrict__ w1cat_bf,
                            float* __restrict__ bias0,
                            float* __restrict__ bias1)
{
    int idx = blockIdx.x * blockDim.x + threadIdx.x;
    int stride = gridDim.x * blockDim.x;
    for (int i = idx; i < HDIM * HDIM; i += stride) {
        __hip_bfloat16 h = __float2bfloat16(w_hh0[i]);
        whh0_bf[i] = *reinterpret_cast<unsigned short*>(&h);
    }
    for (int i = idx; i < HDIM * 2 * HDIM; i += stride) {
        int n = i >> 10;
        int k = i & 1023;
        float v = (k < HDIM) ? w_ih1[n * HDIM + k] : w_hh1[n * HDIM + (k - HDIM)];
        __hip_bfloat16 h = __float2bfloat16(v);
        w1cat_bf[i] = *reinterpret_cast<unsigned short*>(&h);
    }
    for (int i = idx; i < HDIM; i += stride) {
        bias0[i] = b_ih0[i] + b_hh0[i];
        bias1[i] = b_ih1[i] + b_hh1[i];
    }
}

// One workgroup per batch element. 512 threads = 8 waves.
// Thread mapping inside a row-block of 64 rows: r = tid>>3 (row), c = tid&7 (k-chunk).
// Each thread dots 8 consecutive k per pass; butterfly-reduce over c (lanes 0..7 in wave).
__global__ __launch_bounds__(512, 1) void rnn_fused(
    const float* __restrict__ x,
    const float* __restrict__ w_ih0,
    const unsigned short* __restrict__ whh0,
    const unsigned short* __restrict__ w1cat,
    const float* __restrict__ bias0,
    const float* __restrict__ bias1,
    const float* __restrict__ w_lin,
    const float* __restrict__ b_lin,
    float* __restrict__ out)
{
    __shared__ __align__(16) float xs[DDIM];
    __shared__ __align__(16) float h1buf[2][HDIM];
    __shared__ __align__(16) float h2buf[2][HDIM];
    __shared__ __align__(16) float bs0[HDIM];
    __shared__ __align__(16) float bs1[HDIM];
    __shared__ __align__(16) float wl[HDIM];
    __shared__ float red[8];

    const int b   = blockIdx.x;
    const int tid = threadIdx.x;
    const int r   = tid >> 3;
    const int c   = tid & 7;

    for (int i = tid; i < HDIM; i += 512) {
        h1buf[0][i] = 0.f;
        h2buf[0][i] = 0.f;
        bs0[i] = bias0[i];
        bs1[i] = bias1[i];
        wl[i]  = w_lin[i];
    }
    __syncthreads();

    const float* xb = x + (size_t)b * TSTEPS * DDIM;
    int cur = 0;
    const int nbrot = b & 7;   // stagger row-block order across WGs to decorrelate L2 traffic

    for (int t = 0; t < TSTEPS; ++t) {
        if (tid < DDIM) xs[tid] = xb[t * DDIM + tid];
        __syncthreads();

        const float* h1c = h1buf[cur];
        const float* h2c = h2buf[cur];
        float* h1n = h1buf[cur ^ 1];
        float* h2n = h2buf[cur ^ 1];

        // ---- Layer 0: h1n = tanh(w_ih0 @ x_t + whh0 @ h1c + bias0) ----
        for (int nbi = 0; nbi < 8; ++nbi) {
            int nb = (nbi + nbrot) & 7;
            int n  = nb * 64 + r;
            const unsigned short* wrow = whh0 + (size_t)n * HDIM + c * 8;
            ushortx8 wv[8];
            #pragma unroll
            for (int p = 0; p < 8; ++p)
                wv[p] = *reinterpret_cast<const ushortx8*>(wrow + p * 64);
            const float* wirow = w_ih0 + n * DDIM + c * 8;
            floatx4 wiA = *reinterpret_cast<const floatx4*>(wirow);
            floatx4 wiB = *reinterpret_cast<const floatx4*>(wirow + 4);

            float acc = 0.f;
            #pragma unroll
            for (int p = 0; p < 8; ++p) {
                int k0 = p * 64 + c * 8;
                floatx4 hA = *reinterpret_cast<const floatx4*>(&h1c[k0]);
                floatx4 hB = *reinterpret_cast<const floatx4*>(&h1c[k0 + 4]);
                acc += hA.x * b2f(wv[p][0]) + hA.y * b2f(wv[p][1])
                     + hA.z * b2f(wv[p][2]) + hA.w * b2f(wv[p][3])
                     + hB.x * b2f(wv[p][4]) + hB.y * b2f(wv[p][5])
                     + hB.z * b2f(wv[p][6]) + hB.w * b2f(wv[p][7]);
            }
            floatx4 xA = *reinterpret_cast<const floatx4*>(&xs[c * 8]);
            floatx4 xB = *reinterpret_cast<const floatx4*>(&xs[c * 8 + 4]);
            acc += xA.x * wiA.x + xA.y * wiA.y + xA.z * wiA.z + xA.w * wiA.w
                 + xB.x * wiB.x + xB.y * wiB.y + xB.z * wiB.z + xB.w * wiB.w;

            acc += __shfl_xor(acc, 1);
            acc += __shfl_xor(acc, 2);
            acc += __shfl_xor(acc, 4);
            if (c == 0) h1n[n] = tanhf(acc + bs0[n]);
        }
        __syncthreads();

        // ---- Layer 1: h2n = tanh(w_ih1 @ h1n + w_hh1 @ h2c + bias1) via K=1024 concat ----
        for (int nbi = 0; nbi < 8; ++nbi) {
            int nb = (nbi + nbrot) & 7;
            int n  = nb * 64 + r;
            const unsigned short* wrow = w1cat + (size_t)n * (2 * HDIM);
            float acc = 0.f;
            #pragma unroll
            for (int half = 0; half < 2; ++half) {
                ushortx8 wv[8];
                #pragma unroll
                for (int p = 0; p < 8; ++p)
                    wv[p] = *reinterpret_cast<const ushortx8*>(wrow + half * HDIM + p * 64 + c * 8);
                const float* hs = half ? h2c : h1n;
                #pragma unroll
                for (int p = 0; p < 8; ++p) {
                    int k0 = p * 64 + c * 8;
                    floatx4 hA = *reinterpret_cast<const floatx4*>(&hs[k0]);
                    floatx4 hB = *reinterpret_cast<const floatx4*>(&hs[k0 + 4]);
                    acc += hA.x * b2f(wv[p][0]) + hA.y * b2f(wv[p][1])
                         + hA.z * b2f(wv[p][2]) + hA.w * b2f(wv[p][3])
                         + hB.x * b2f(wv[p][4]) + hB.y * b2f(wv[p][5])
                         + hB.z * b2f(wv[p][6]) + hB.w * b2f(wv[p][7]);
                }
            }
            acc += __shfl_xor(acc, 1);
            acc += __shfl_xor(acc, 2);
            acc += __shfl_xor(acc, 4);
            if (c == 0) h2n[n] = tanhf(acc + bs1[n]);
        }
        cur ^= 1;
        __syncthreads();
    }

    // ---- Final linear: out[b] = h2 . w_lin + b_lin ----
    float v = h2buf[cur][tid] * wl[tid];
    #pragma unroll
    for (int off = 1; off < 64; off <<= 1) v += __shfl_xor(v, off);
    if ((tid & 63) == 0) red[tid >> 6] = v;
    __syncthreads();
    if (tid == 0) {
        float s = b_lin[0];
        #pragma unroll
        for (int i = 0; i < 8; ++i) s += red[i];
        out[b] = s;
    }
}

extern "C" void kernel_launch(void* const* d_in, const int* in_sizes, int n_in,
                              void* d_out, int out_size, void* d_ws, size_t ws_size,
                              hipStream_t stream) {
    const float* x     = (const float*)d_in[0];
    const float* w_ih0 = (const float*)d_in[1];
    const float* w_hh0 = (const float*)d_in[2];
    const float* b_ih0 = (const float*)d_in[3];
    const float* b_hh0 = (const float*)d_in[4];
    const float* w_ih1 = (const float*)d_in[5];
    const float* w_hh1 = (const float*)d_in[6];
    const float* b_ih1 = (const float*)d_in[7];
    const float* b_hh1 = (const float*)d_in[8];
    const float* w_lin = (const float*)d_in[9];
    const float* b_lin = (const float*)d_in[10];
    float* out = (float*)d_out;

    char* ws = (char*)d_ws;
    unsigned short* whh0_bf  = (unsigned short*)ws;                       // 512 KB
    unsigned short* w1cat_bf = (unsigned short*)(ws + 524288);            // 1 MB
    float* bias0 = (float*)(ws + 524288 + 1048576);                       // 2 KB
    float* bias1 = (float*)(ws + 524288 + 1048576 + 2048);                // 2 KB

    prep_kernel<<<512, 256, 0, stream>>>(w_hh0, w_ih1, w_hh1, b_ih0, b_hh0,
                                         b_ih1, b_hh1, whh0_bf, w1cat_bf, bias0, bias1);
    rnn_fused<<<BATCH, 512, 0, stream>>>(x, w_ih0, whh0_bf, w1cat_bf,
                                         bias0, bias1, w_lin, b_lin, out);
}